// Round 1
// 674.605 us; speedup vs baseline: 1.0242x; 1.0242x over previous
//
#include <hip/hip_runtime.h>

// LIF multistep: T=4, VTHR=1.0, TAU=0.5, hard reset.
// x: (T, 32, 512, 1024) fp32.  Outputs: spikes (T*N), mems (T*N) concatenated.
// N = 16,777,216 elements per timestep (2^24), n4 = 2^22 float4 groups.
// Memory-bound: 256 MiB read + 512 MiB write -> ~128 us roofline at 6.3 TB/s.
//
// R1 changes vs baseline (340 us kernel, ~2.4 TB/s effective):
//  - nontemporal loads/stores (nt bit): zero-reuse streams should not
//    allocate in L2/LLC; dirty-line thrash from 537 MB of output writes
//    was competing with x fetches.
//  - 2x float4 per thread per stream (two coalesced slots offset by
//    blockDim), all 8 loads hoisted ahead of compute: 128 B/lane in
//    flight, half the per-byte issue overhead.

#define LIF_T 4

typedef float f32x4 __attribute__((ext_vector_type(4)));

__global__ __launch_bounds__(256) void lif_kernel(
    const f32x4* __restrict__ x,
    f32x4* __restrict__ spikes,
    f32x4* __restrict__ mems,
    long n4)   // float4 groups per timestep
{
    const float VTHR = 1.0f;
    const float TAU  = 0.5f;

    // Two coalesced slots per thread: [block*512 + tid] and [.. + 256].
    long i0 = (long)blockIdx.x * 512 + threadIdx.x;
    long i1 = i0 + 256;
    const bool p0 = i0 < n4;
    const bool p1 = i1 < n4;

    // Hoist all 8 nontemporal loads (4 timesteps x 2 slots) for max MLP.
    f32x4 xa[LIF_T], xb[LIF_T];
#pragma unroll
    for (int t = 0; t < LIF_T; ++t) {
        if (p0) xa[t] = __builtin_nontemporal_load(&x[(size_t)t * n4 + i0]);
        if (p1) xb[t] = __builtin_nontemporal_load(&x[(size_t)t * n4 + i1]);
    }

    f32x4 va = {0.f, 0.f, 0.f, 0.f};
    f32x4 vb = {0.f, 0.f, 0.f, 0.f};

#pragma unroll
    for (int t = 0; t < LIF_T; ++t) {
        if (p0) {
            f32x4 u = va + xa[t];          // integrate
            f32x4 s;
#pragma unroll
            for (int c = 0; c < 4; ++c) {
                bool fire = u[c] > VTHR;   // ZIF forward = Heaviside (strict >)
                s[c] = fire ? 1.f : 0.f;
                u[c] = fire ? 0.f : u[c];  // hard reset, exact zero
            }
            __builtin_nontemporal_store(s, &spikes[(size_t)t * n4 + i0]);
            __builtin_nontemporal_store(u, &mems[(size_t)t * n4 + i0]);
            va = u * TAU;                  // decay carried state
        }
        if (p1) {
            f32x4 u = vb + xb[t];
            f32x4 s;
#pragma unroll
            for (int c = 0; c < 4; ++c) {
                bool fire = u[c] > VTHR;
                s[c] = fire ? 1.f : 0.f;
                u[c] = fire ? 0.f : u[c];
            }
            __builtin_nontemporal_store(s, &spikes[(size_t)t * n4 + i1]);
            __builtin_nontemporal_store(u, &mems[(size_t)t * n4 + i1]);
            vb = u * TAU;
        }
    }
}

extern "C" void kernel_launch(void* const* d_in, const int* in_sizes, int n_in,
                              void* d_out, int out_size, void* d_ws, size_t ws_size,
                              hipStream_t stream) {
    const float* x = (const float*)d_in[0];
    float* out = (float*)d_out;

    long total = (long)in_sizes[0];       // T * N
    long N = total / LIF_T;               // elements per timestep
    long n4 = N / 4;                      // float4 groups per timestep

    f32x4* spikes = (f32x4*)out;                    // first T*N floats
    f32x4* mems   = (f32x4*)(out + total);          // next T*N floats

    int block = 256;
    long grid = (n4 + 511) / 512;         // 512 float4 groups per block

    lif_kernel<<<dim3((unsigned)grid), dim3(block), 0, stream>>>(
        (const f32x4*)x, spikes, mems, n4);
}